// Round 19
// baseline (249.696 us; speedup 1.0000x reference)
//
#include <hip/hip_runtime.h>
#include <math.h>

#define TT 16
#define HH 112
#define WD 112
#define CC 96
#define NHEADS 3
#define HD 32
#define NN 98          // window tokens 2*7*7
#define NWIN 2048      // 8*16*16
#define NTOK 200704    // T*H*W == NWIN*NN
#define MLPH 384
#define SXP 104        // row stride (bf16) LDS tiles (208B rows, 16B aligned)
#define SQP 40         // row stride (bf16) per-head sQ/sK
#define SVP 136        // row stride (bf16) sVt/sP
#define SH2P 200       // row stride (bf16) sH half (192 cols + 8 pad)
#define SX1P 100       // row stride (bf16) sX1

typedef unsigned int  u32;
typedef unsigned short u16;
typedef float f32x4 __attribute__((ext_vector_type(4)));
typedef short bf16x8 __attribute__((ext_vector_type(8)));

__device__ inline u16 f2bf(float f) {
  u32 u = __float_as_uint(f);
  u += 0x7fffu + ((u >> 16) & 1u);
  return (u16)(u >> 16);
}
__device__ inline float bflo(u32 u) { return __uint_as_float(u << 16); }
__device__ inline float bfhi(u32 u) { return __uint_as_float(u & 0xffff0000u); }

#define MFMA16(a, b, c) __builtin_amdgcn_mfma_f32_16x16x32_bf16((a), (b), (c), 0, 0, 0)

// ---------------- K0a: transpose all weights to bf16 col-major ----------------
__global__ __launch_bounds__(256) void wprep_kernel(
    const float* __restrict__ qkv_w, const float* __restrict__ proj_w,
    const float* __restrict__ fc1_w, const float* __restrict__ fc2_w,
    u16* __restrict__ qkv_wT, u16* __restrict__ proj_wT,
    u16* __restrict__ fc1_wT, u16* __restrict__ fc2_wT) {
  int idx = blockIdx.x * 256 + threadIdx.x;
  if (idx < 27648) {                       // qkv_wT[col][c]
    int col = idx / CC, c = idx - col * CC;
    qkv_wT[idx] = f2bf(qkv_w[c * (3 * CC) + col]);
    return;
  }
  idx -= 27648;
  if (idx < 9216) {                        // proj_wT[col][c]
    int col = idx / CC, c = idx - col * CC;
    proj_wT[idx] = f2bf(proj_w[c * CC + col]);
    return;
  }
  idx -= 9216;
  if (idx < 36864) {                       // fc1_wT[j][c]
    int j = idx / CC, c = idx - j * CC;
    fc1_wT[idx] = f2bf(fc1_w[c * MLPH + j]);
    return;
  }
  idx -= 36864;
  if (idx < 36864) {                       // fc2_wT[c][j]
    int c = idx / MLPH, j = idx - c * MLPH;
    fc2_wT[idx] = f2bf(fc2_w[j * CC + c]);
  }
}

// ---------------- K0b: padded bias table biasTP[head][q:112][kv:128] ----------------
// kv pad (>=98): -30000 (kills pad cols in softmax); q pad rows: 0 (unused).
__global__ __launch_bounds__(256) void bias_kernel(const float* __restrict__ rpb,
                                                   float* __restrict__ biasTP) {
  int idx = blockIdx.x * 256 + threadIdx.x;
  if (idx >= NHEADS * 112 * 128) return;
  int head = idx / (112 * 128);
  int r = idx - head * 112 * 128;
  int q = r / 128, kv = r - q * 128;
  float v;
  if (kv >= NN) v = -30000.f;
  else if (q >= NN) v = 0.f;
  else {
    int itq = q / 49, rq = q - itq * 49, ihq = rq / 7, iwq = rq - ihq * 7;
    int itk = kv / 49, rk = kv - itk * 49, ihk = rk / 7, iwk = rk - ihk * 7;
    int ridx = (itq - itk + 1) * 169 + (ihq - ihk + 6) * 13 + (iwq - iwk + 6);
    v = rpb[ridx * NHEADS + head];
  }
  biasTP[idx] = v;
}

// ---------------- K0c: LN1 + shift-roll + window gather -> xnw[widx][112][96] bf16 ----------------
__global__ __launch_bounds__(256) void ln1_kernel(
    const float* __restrict__ x, const float* __restrict__ g1, const float* __restrict__ b1,
    u16* __restrict__ xnw)
{
  const int tid = threadIdx.x;
  const int row = blockIdx.x * 64 + (tid >> 2);   // 0 .. NWIN*112-1
  const int qd = tid & 3;                          // quarter: 24 channels
  const int widx = row / 112;
  const int n = row - widx * 112;
  u16* dst = xnw + (size_t)row * CC + qd * 24;
  if (n >= NN) {                                   // pad row -> zeros
    uint4 z = {0u, 0u, 0u, 0u};
    *(uint4*)(dst) = z; *(uint4*)(dst + 8) = z; *(uint4*)(dst + 16) = z;
    return;
  }
  int it = n / 49, r = n - it * 49, ih = r / 7, iw = r - ih * 7;
  int ww = widx & 15, hw = (widx >> 4) & 15, tw = widx >> 8;
  int t = tw * 2 + it + 1; if (t >= TT) t -= TT;
  int h = hw * 7 + ih + 3; if (h >= HH) h -= HH;
  int w = ww * 7 + iw + 3; if (w >= WD) w -= WD;
  const float* src = x + ((size_t)(t * HH + h) * WD + w) * CC + qd * 24;
  float v[24];
  #pragma unroll
  for (int i = 0; i < 24; i += 4) {
    float4 f = *(const float4*)(src + i);
    v[i] = f.x; v[i + 1] = f.y; v[i + 2] = f.z; v[i + 3] = f.w;
  }
  float sm = 0.f;
  #pragma unroll
  for (int i = 0; i < 24; ++i) sm += v[i];
  sm += __shfl_xor(sm, 1, 64);
  sm += __shfl_xor(sm, 2, 64);
  float mu = sm * (1.f / CC);
  float sq = 0.f;
  #pragma unroll
  for (int i = 0; i < 24; ++i) { float d = v[i] - mu; sq += d * d; }
  sq += __shfl_xor(sq, 1, 64);
  sq += __shfl_xor(sq, 2, 64);
  float inv = rsqrtf(sq * (1.f / CC) + 1e-5f);
  u16 o[24];
  #pragma unroll
  for (int i = 0; i < 24; ++i) {
    int c = qd * 24 + i;
    o[i] = f2bf((v[i] - mu) * inv * g1[c] + b1[c]);
  }
  *(uint4*)(dst)      = *(const uint4*)(o);
  *(uint4*)(dst + 8)  = *(const uint4*)(o + 8);
  *(uint4*)(dst + 16) = *(const uint4*)(o + 16);
}

// ---------------- K1: per-(window,head) QKV + attention (MFMA) ----------------
// bias folded into MFMA C-init (padded biasTP) + s_setprio around MFMA clusters.
__global__ __launch_bounds__(256, 4) void attn_kernel(
    const u16* __restrict__ xnw, const u16* __restrict__ qkv_wT, const float* __restrict__ qkv_b,
    const float* __restrict__ biasTP, u16* __restrict__ att)
{
  // union buffer: phases 1-2 -> sQ[112][40] + sK[112][40]; phases 3-4 -> sP[112][136]
  __shared__ __align__(16) u16 sUni[112 * SVP];   // 30464 B
  __shared__ __align__(16) u16 sVt[32 * SVP];     //  8704 B  [d][kv]
  __shared__ int sReg[112];

  u16* sQ = sUni;
  u16* sK = sUni + 112 * SQP;
  u16* sP = sUni;

  const int tid  = threadIdx.x;
  const int bid  = blockIdx.x;
  const int widx = bid / 3;
  const int head = bid - widx * 3;
  const int ww = widx & 15, hw = (widx >> 4) & 15, tw = widx >> 8;
  const bool bnd = (tw == 7) || (hw == 15) || (ww == 15);
  const int wid = tid >> 6;          // wave 0..3
  const int lane = tid & 63;
  const int g  = lane >> 4;          // lane group 0..3
  const int cl = lane & 15;          // col-in-tile
  const int mt1ok = (wid + 4) < 7;   // wave 3 has only one m-tile

  // ---- EARLY: prefetch phase-1 A-frags from global (consumed after phase-0 barrier)
  bf16x8 xa[2][3];
  {
    const u16* arow0 = xnw + ((size_t)widx * 112 + wid * 16 + cl) * CC + 8 * g;
    xa[0][0] = *(const bf16x8*)(arow0);
    xa[0][1] = *(const bf16x8*)(arow0 + 32);
    xa[0][2] = *(const bf16x8*)(arow0 + 64);
    const int mtb = mt1ok ? (wid + 4) : wid;
    const u16* arow1 = xnw + ((size_t)widx * 112 + mtb * 16 + cl) * CC + 8 * g;
    xa[1][0] = *(const bf16x8*)(arow1);
    xa[1][1] = *(const bf16x8*)(arow1 + 32);
    xa[1][2] = *(const bf16x8*)(arow1 + 64);
  }

  // ---- phase 0: zero sVt (pad kv cols must be 0) + region ids
  for (int i = tid; i < 32 * SVP / 2; i += 256) ((u32*)sVt)[i] = 0;
  if (tid < 112) {
    int n = tid;
    int reg = 0;
    if (n < NN) {
      int it = n / 49, r = n - it * 49, ih = r / 7, iw = r - ih * 7;
      int ts = tw * 2 + it, hs = hw * 7 + ih, ws2 = ww * 7 + iw;
      int rt = ts < TT - 2 ? 0 : (ts < TT - 1 ? 1 : 2);
      int rh = hs < HH - 7 ? 0 : (hs < HH - 3 ? 1 : 2);
      int rw = ws2 < WD - 7 ? 0 : (ws2 < WD - 3 ? 1 : 2);
      reg = rt * 9 + rh * 3 + rw;
    }
    sReg[n] = reg;
  }
  __syncthreads();

  // ---- phase 1: QKV slice (nt-outer: B loaded once, feeds both m-tiles)
  {
    const float scale = 0.17677669529663687f;   // 32^-0.5
    #pragma unroll
    for (int nt = 0; nt < 6; ++nt) {
      const int sec = nt >> 1;                      // 0=Q 1=K 2=V
      const int col = sec * 96 + head * 32 + (nt & 1) * 16 + cl;
      const u16* brow = qkv_wT + (size_t)col * CC + 8 * g;
      bf16x8 b0 = *(const bf16x8*)(brow);
      bf16x8 b1 = *(const bf16x8*)(brow + 32);
      bf16x8 b2 = *(const bf16x8*)(brow + 64);
      const float bias = qkv_b[col];
      #pragma unroll
      for (int mi = 0; mi < 2; ++mi) {
        const int mt = wid + mi * 4;
        if (mi == 1 && !mt1ok) continue;
        f32x4 acc = {0.f, 0.f, 0.f, 0.f};
        acc = MFMA16(xa[mi][0], b0, acc);
        acc = MFMA16(xa[mi][1], b1, acc);
        acc = MFMA16(xa[mi][2], b2, acc);
        #pragma unroll
        for (int r = 0; r < 4; ++r) {
          const int row = mt * 16 + 4 * g + r;
          const float v = acc[r] + bias;
          if (sec == 0)      sQ[row * SQP + (nt & 1) * 16 + cl] = f2bf(v * scale);
          else if (sec == 1) sK[row * SQP + (nt & 1) * 16 + cl] = f2bf(v);
          else               sVt[((nt & 1) * 16 + cl) * SVP + row] = f2bf(v);
        }
      }
    }
  }
  __syncthreads();

  // ---- phase 2: QK^T (bias in MFMA C-init) + mask + in-register softmax
  float sv[2][7][4];
  #pragma unroll
  for (int mi = 0; mi < 2; ++mi) {
    const int mt = wid + mi * 4;
    if (mt >= 7) continue;
    const int q0 = mt * 16 + 4 * g;
    bf16x8 a = *(const bf16x8*)&sQ[(mt * 16 + cl) * SQP + 8 * g];
    __builtin_amdgcn_s_setprio(1);
    #pragma unroll
    for (int nt = 0; nt < 7; ++nt) {
      bf16x8 b = *(const bf16x8*)&sK[(nt * 16 + cl) * SQP + 8 * g];
      const float* bp = biasTP + ((size_t)(head * 112 + q0) * 128 + nt * 16 + cl);
      f32x4 acc = {bp[0], bp[128], bp[256], bp[384]};
      acc = MFMA16(a, b, acc);
      #pragma unroll
      for (int r = 0; r < 4; ++r) sv[mi][nt][r] = acc[r];
    }
    __builtin_amdgcn_s_setprio(0);
    if (bnd) {
      #pragma unroll
      for (int nt = 0; nt < 7; ++nt) {
        const int kv = nt * 16 + cl;
        #pragma unroll
        for (int r = 0; r < 4; ++r) {
          if (sReg[q0 + r] != sReg[kv]) sv[mi][nt][r] -= 100.f;
        }
      }
    }
    #pragma unroll
    for (int r = 0; r < 4; ++r) {
      float mx = sv[mi][0][r];
      #pragma unroll
      for (int nt = 1; nt < 7; ++nt) mx = fmaxf(mx, sv[mi][nt][r]);
      #pragma unroll
      for (int d = 1; d < 16; d <<= 1) mx = fmaxf(mx, __shfl_xor(mx, d, 64));
      float sm = 0.f;
      #pragma unroll
      for (int nt = 0; nt < 7; ++nt) { float p = __expf(sv[mi][nt][r] - mx); sv[mi][nt][r] = p; sm += p; }
      #pragma unroll
      for (int d = 1; d < 16; d <<= 1) sm += __shfl_xor(sm, d, 64);
      const float inv = 1.f / sm;
      #pragma unroll
      for (int nt = 0; nt < 7; ++nt) sv[mi][nt][r] *= inv;
    }
  }
  __syncthreads();   // all Q/K reads complete before P overwrites the union buffer

  // ---- phase 3: write P (bf16) + zero pad cols 112..127
  #pragma unroll
  for (int mi = 0; mi < 2; ++mi) {
    const int mt = wid + mi * 4;
    if (mt >= 7) continue;
    #pragma unroll
    for (int r = 0; r < 4; ++r) {
      const int q = mt * 16 + 4 * g + r;
      u16* prow = &sP[q * SVP];
      #pragma unroll
      for (int nt = 0; nt < 7; ++nt) prow[nt * 16 + cl] = f2bf(sv[mi][nt][r]);
      prow[112 + cl] = 0;
    }
  }
  __syncthreads();

  // ---- phase 4: PV (MFMA, K=128) + store
  for (int t = wid; t < 14; t += 4) {
    const int mt = t >> 1, ntd = t & 1;
    f32x4 acc = {0.f, 0.f, 0.f, 0.f};
    __builtin_amdgcn_s_setprio(1);
    #pragma unroll
    for (int ks = 0; ks < 4; ++ks) {
      bf16x8 a = *(const bf16x8*)&sP[(mt * 16 + cl) * SVP + ks * 32 + 8 * g];
      bf16x8 b = *(const bf16x8*)&sVt[(ntd * 16 + cl) * SVP + ks * 32 + 8 * g];
      acc = MFMA16(a, b, acc);
    }
    __builtin_amdgcn_s_setprio(0);
    #pragma unroll
    for (int r = 0; r < 4; ++r) {
      const int q = mt * 16 + 4 * g + r;
      if (q < NN)
        att[((size_t)widx * NN + q) * CC + head * 32 + ntd * 16 + cl] = f2bf(acc[r]);
    }
  }
}

// ---------------- K2: fused proj + residual + LN2 + FC1 + GELU + FC2 + residual ----------------
// 2x B-reuse (wave owns both m-tiles) + LDS 25.9KB -> 6 blocks/CU:
// proj A-frags direct from global (no sA staging phase); sH split into two 192-col halves.
__global__ __launch_bounds__(128, 3) void pm_kernel(
    const u16* __restrict__ att, const u16* __restrict__ proj_wT, const float* __restrict__ proj_b,
    const float* __restrict__ x,
    const float* __restrict__ g2, const float* __restrict__ b2,
    const u16* __restrict__ fc1_wT, const float* __restrict__ fc1_b,
    const u16* __restrict__ fc2_wT, const float* __restrict__ fc2_b,
    float* __restrict__ out)
{
  __shared__ __align__(16) u16 sHh[32 * SH2P];   // 12800 B (H half: 192 cols)
  __shared__ __align__(16) u16 sX1[32 * SX1P];   //  6400 B
  __shared__ __align__(16) u16 sXn[32 * SXP];    //  6656 B
  // total 25856 B -> 6 blocks/CU (12 waves)

  const int tid  = threadIdx.x;
  const int base = blockIdx.x * 32;              // window-token base
  const int hnt  = tid >> 6;        // wave = nt-half (0..1)
  const int lane = tid & 63, g = lane >> 4, cl = lane & 15;

  // ---- P-1: natural-row indices (both m-tiles) + EARLY x-residual prefetch
  u32 nr[2][4];
  #pragma unroll
  for (int mt = 0; mt < 2; ++mt) {
    #pragma unroll
    for (int r = 0; r < 4; ++r) {
      int tok = base + mt * 16 + 4 * g + r;
      int widx = tok / NN, n = tok - widx * NN;
      int ww = widx & 15, hw = (widx >> 4) & 15, tw = widx >> 8;
      int it = n / 49, rr = n - it * 49, ih = rr / 7, iw = rr - ih * 7;
      int t = tw * 2 + it + 1; if (t >= TT) t -= TT;
      int h = hw * 7 + ih + 3; if (h >= HH) h -= HH;
      int w = ww * 7 + iw + 3; if (w >= WD) w -= WD;
      nr[mt][r] = (u32)((t * HH + h) * WD + w);
    }
  }
  float xres[3][2][4];
  #pragma unroll
  for (int j = 0; j < 3; ++j) {
    const int col = (hnt * 3 + j) * 16 + cl;
    #pragma unroll
    for (int mt = 0; mt < 2; ++mt)
      #pragma unroll
      for (int r = 0; r < 4; ++r)
        xres[j][mt][r] = x[(size_t)nr[mt][r] * CC + col];
  }

  // ---- P1: proj GEMM [32x96]@[96x96]; A direct from global att (contiguous rows);
  // B loaded once per nt, used for BOTH m-tiles
  float x1v[3][2][4];
  {
    bf16x8 a[2][3];
    #pragma unroll
    for (int mt = 0; mt < 2; ++mt) {
      const u16* aRow = att + (size_t)(base + mt * 16 + cl) * CC + 8 * g;
      a[mt][0] = *(const bf16x8*)(aRow);
      a[mt][1] = *(const bf16x8*)(aRow + 32);
      a[mt][2] = *(const bf16x8*)(aRow + 64);
    }
    #pragma unroll
    for (int j = 0; j < 3; ++j) {
      const int nt = hnt * 3 + j;
      const u16* bRow = proj_wT + (nt * 16 + cl) * CC + 8 * g;
      bf16x8 b0 = *(const bf16x8*)(bRow);
      bf16x8 b1 = *(const bf16x8*)(bRow + 32);
      bf16x8 b2 = *(const bf16x8*)(bRow + 64);
      const float bc = proj_b[nt * 16 + cl];
      #pragma unroll
      for (int mt = 0; mt < 2; ++mt) {
        f32x4 acc = {0.f, 0.f, 0.f, 0.f};
        acc = MFMA16(a[mt][0], b0, acc);
        acc = MFMA16(a[mt][1], b1, acc);
        acc = MFMA16(a[mt][2], b2, acc);
        #pragma unroll
        for (int r = 0; r < 4; ++r) {
          const int row = mt * 16 + 4 * g + r;
          const float v = acc[r] + bc + xres[j][mt][r];
          x1v[j][mt][r] = v;
          sX1[row * SX1P + nt * 16 + cl] = f2bf(v);
        }
      }
    }
  }
  __syncthreads();

  // ---- P2: LN2 from sX1 (bf16): token = tid>>2 (32), sub = tid&3 (24 ch); 4-lane shfl
  {
    const int tok = tid >> 2, sub = tid & 3;
    const u16* p = &sX1[tok * SX1P + sub * 24];
    float v[24];
    #pragma unroll
    for (int k = 0; k < 12; ++k) {
      u32 u = *(const u32*)(p + 2 * k);
      v[2 * k] = bflo(u); v[2 * k + 1] = bfhi(u);
    }
    float sm = 0.f;
    #pragma unroll
    for (int i = 0; i < 24; ++i) sm += v[i];
    sm += __shfl_xor(sm, 1, 64);
    sm += __shfl_xor(sm, 2, 64);
    float mu = sm * (1.f / CC);
    float sq = 0.f;
    #pragma unroll
    for (int i = 0; i < 24; ++i) { float d = v[i] - mu; sq += d * d; }
    sq += __shfl_xor(sq, 1, 64);
    sq += __shfl_xor(sq, 2, 64);
    float inv = rsqrtf(sq * (1.f / CC) + 1e-5f);
    u16 o[24];
    #pragma unroll
    for (int i = 0; i < 24; ++i) {
      int c = sub * 24 + i;
      o[i] = f2bf((v[i] - mu) * inv * g2[c] + b2[c]);
    }
    u16* dst = &sXn[tok * SXP + sub * 24];
    *(uint4*)(dst)      = *(const uint4*)(o);
    *(uint4*)(dst + 8)  = *(const uint4*)(o + 8);
    *(uint4*)(dst + 16) = *(const uint4*)(o + 16);
  }
  __syncthreads();

  // ---- P3/P4: FC1(+GELU) and FC2 in two 192-col halves through sHh
  f32x4 acc2[3][2];
  #pragma unroll
  for (int j = 0; j < 3; ++j)
    #pragma unroll
    for (int mt = 0; mt < 2; ++mt) { f32x4 z = {0.f, 0.f, 0.f, 0.f}; acc2[j][mt] = z; }

  bf16x8 aXn[2][3];
  #pragma unroll
  for (int mt = 0; mt < 2; ++mt) {
    const u16* ap = &sXn[(mt * 16 + cl) * SXP + 8 * g];
    aXn[mt][0] = *(const bf16x8*)(ap);
    aXn[mt][1] = *(const bf16x8*)(ap + 32);
    aXn[mt][2] = *(const bf16x8*)(ap + 64);
  }

  #pragma unroll
  for (int hf = 0; hf < 2; ++hf) {
    // FC1 half: 6 nt per wave (B once -> 2 m-tiles), prefetch 1 ahead
    {
      const int nt0 = hf * 12 + hnt * 6;
      const u16* bPtr = fc1_wT + ((size_t)(nt0 * 16 + cl)) * CC + 8 * g;
      bf16x8 b0 = *(const bf16x8*)(bPtr);
      bf16x8 b1 = *(const bf16x8*)(bPtr + 32);
      bf16x8 b2 = *(const bf16x8*)(bPtr + 64);
      #pragma unroll
      for (int j = 0; j < 6; ++j) {
        bf16x8 c0 = b0, c1 = b1, c2 = b2;
        if (j < 5) {
          bPtr += 16 * CC;
          b0 = *(const bf16x8*)(bPtr);
          b1 = *(const bf16x8*)(bPtr + 32);
          b2 = *(const bf16x8*)(bPtr + 64);
        }
        const int nt = nt0 + j;
        const float bj = fc1_b[nt * 16 + cl];
        const int lcol = (hnt * 6 + j) * 16 + cl;       // 0..191 within this half
        #pragma unroll
        for (int mt = 0; mt < 2; ++mt) {
          f32x4 acc = {0.f, 0.f, 0.f, 0.f};
          acc = MFMA16(aXn[mt][0], c0, acc);
          acc = MFMA16(aXn[mt][1], c1, acc);
          acc = MFMA16(aXn[mt][2], c2, acc);
          #pragma unroll
          for (int r = 0; r < 4; ++r) {
            float v = acc[r] + bj;
            // tanh-GELU: v*e/(e+1), e = exp(v*(1.59576912 + 0.07135481*v^2))
            float p2 = v * v;
            float aa = v * fmaf(0.07135481f, p2, 1.59576912f);
            float e  = __expf(aa);
            float gl = v * e * __builtin_amdgcn_rcpf(e + 1.f);
            sHh[(mt * 16 + 4 * g + r) * SH2P + lcol] = f2bf(gl);
          }
        }
      }
    }
    __syncthreads();
    // FC2 partial (k-slice hf*192..+192): B once per (nt, ks-set) -> 2 m-tiles
    {
      bf16x8 a[2][6];
      #pragma unroll
      for (int mt = 0; mt < 2; ++mt) {
        const u16* aBase = &sHh[(mt * 16 + cl) * SH2P + 8 * g];
        #pragma unroll
        for (int ks = 0; ks < 6; ++ks) a[mt][ks] = *(const bf16x8*)(aBase + 32 * ks);
      }
      #pragma unroll
      for (int j = 0; j < 3; ++j) {
        const int nt = hnt * 3 + j;
        const u16* bBase = fc2_wT + (size_t)(nt * 16 + cl) * MLPH + hf * 192 + 8 * g;
        #pragma unroll
        for (int ks = 0; ks < 6; ++ks) {
          bf16x8 b = *(const bf16x8*)(bBase + 32 * ks);
          #pragma unroll
          for (int mt = 0; mt < 2; ++mt)
            acc2[j][mt] = MFMA16(a[mt][ks], b, acc2[j][mt]);
        }
      }
    }
    if (hf == 0) __syncthreads();   // sHh reads done before half-1 FC1 overwrites
  }

  // ---- epilogue: out = x1(reg) + fc2_b + acc2
  #pragma unroll
  for (int j = 0; j < 3; ++j) {
    const int nt = hnt * 3 + j;
    const float bc = fc2_b[nt * 16 + cl];
    #pragma unroll
    for (int mt = 0; mt < 2; ++mt)
      #pragma unroll
      for (int r = 0; r < 4; ++r)
        out[(size_t)nr[mt][r] * CC + nt * 16 + cl] = x1v[j][mt][r] + acc2[j][mt][r] + bc;
  }
}

extern "C" void kernel_launch(void* const* d_in, const int* in_sizes, int n_in,
                              void* d_out, int out_size, void* d_ws, size_t ws_size,
                              hipStream_t stream) {
  const float* x      = (const float*)d_in[0];
  const float* g1     = (const float*)d_in[1];
  const float* b1     = (const float*)d_in[2];
  const float* qkv_w  = (const float*)d_in[3];
  const float* qkv_b  = (const float*)d_in[4];
  const float* rpb    = (const float*)d_in[5];
  const float* proj_w = (const float*)d_in[6];
  const float* proj_b = (const float*)d_in[7];
  const float* g2     = (const float*)d_in[8];
  const float* b2     = (const float*)d_in[9];
  const float* fc1_w  = (const float*)d_in[10];
  const float* fc1_b  = (const float*)d_in[11];
  const float* fc2_w  = (const float*)d_in[12];
  const float* fc2_b  = (const float*)d_in[13];

  char* ws = (char*)d_ws;
  u16*   att    = (u16*)ws;                                   // NTOK*96 bf16 = 38.5 MB
  u16*   xnw    = (u16*)(ws + (size_t)NTOK * CC * 2);         // NWIN*112*96 bf16 = 44 MB
  char*  wtail  = ws + (size_t)NTOK * CC * 2 + (size_t)NWIN * 112 * CC * 2;
  float* biasTP = (float*)wtail;                              // 3*112*128*4 = 172032 B
  u16*   qkv_wT = (u16*)(wtail + 172032);                     // 55296 B
  u16*   proj_wT= (u16*)(wtail + 172032 + 55296);             // 18432 B
  u16*   fc1_wT = (u16*)(wtail + 172032 + 55296 + 18432);     // 73728 B
  u16*   fc2_wT = (u16*)(wtail + 172032 + 55296 + 18432 + 73728); // 73728 B

  wprep_kernel<<<(27648 + 9216 + 36864 + 36864 + 255) / 256, 256, 0, stream>>>(
      qkv_w, proj_w, fc1_w, fc2_w, qkv_wT, proj_wT, fc1_wT, fc2_wT);
  bias_kernel<<<(NHEADS * 112 * 128 + 255) / 256, 256, 0, stream>>>(rpb, biasTP);
  ln1_kernel<<<NWIN * 112 / 64, 256, 0, stream>>>(x, g1, b1, xnw);
  attn_kernel<<<NWIN * NHEADS, 256, 0, stream>>>(xnw, qkv_wT, qkv_b, biasTP, att);
  pm_kernel<<<NTOK / 32, 128, 0, stream>>>(att, proj_wT, proj_b, x, g2, b2,
                                           fc1_wT, fc1_b, fc2_wT, fc2_b, (float*)d_out);
}

// Round 20
// 218.160 us; speedup vs baseline: 1.1446x; 1.1446x over previous
//
#include <hip/hip_runtime.h>
#include <math.h>

#define TT 16
#define HH 112
#define WD 112
#define CC 96
#define NHEADS 3
#define HD 32
#define NN 98          // window tokens 2*7*7
#define NWIN 2048      // 8*16*16
#define NTOK 200704    // T*H*W == NWIN*NN
#define MLPH 384
#define SXP 104        // row stride (bf16) LDS tiles (208B rows, 16B aligned)
#define SQP 40         // row stride (bf16) per-head sQ/sK
#define SVP 136        // row stride (bf16) sVt/sP
#define SH2P 200       // row stride (bf16) sH half (192 cols + 8 pad)
#define SX1P 100       // row stride (bf16) sX1

typedef unsigned int  u32;
typedef unsigned short u16;
typedef float f32x4 __attribute__((ext_vector_type(4)));
typedef short bf16x8 __attribute__((ext_vector_type(8)));

__device__ inline u16 f2bf(float f) {
  u32 u = __float_as_uint(f);
  u += 0x7fffu + ((u >> 16) & 1u);
  return (u16)(u >> 16);
}
__device__ inline float bflo(u32 u) { return __uint_as_float(u << 16); }
__device__ inline float bfhi(u32 u) { return __uint_as_float(u & 0xffff0000u); }

#define MFMA16(a, b, c) __builtin_amdgcn_mfma_f32_16x16x32_bf16((a), (b), (c), 0, 0, 0)

// ---------------- K0a: transpose all weights to bf16 col-major ----------------
__global__ __launch_bounds__(256) void wprep_kernel(
    const float* __restrict__ qkv_w, const float* __restrict__ proj_w,
    const float* __restrict__ fc1_w, const float* __restrict__ fc2_w,
    u16* __restrict__ qkv_wT, u16* __restrict__ proj_wT,
    u16* __restrict__ fc1_wT, u16* __restrict__ fc2_wT) {
  int idx = blockIdx.x * 256 + threadIdx.x;
  if (idx < 27648) {                       // qkv_wT[col][c]
    int col = idx / CC, c = idx - col * CC;
    qkv_wT[idx] = f2bf(qkv_w[c * (3 * CC) + col]);
    return;
  }
  idx -= 27648;
  if (idx < 9216) {                        // proj_wT[col][c]
    int col = idx / CC, c = idx - col * CC;
    proj_wT[idx] = f2bf(proj_w[c * CC + col]);
    return;
  }
  idx -= 9216;
  if (idx < 36864) {                       // fc1_wT[j][c]
    int j = idx / CC, c = idx - j * CC;
    fc1_wT[idx] = f2bf(fc1_w[c * MLPH + j]);
    return;
  }
  idx -= 36864;
  if (idx < 36864) {                       // fc2_wT[c][j]
    int c = idx / MLPH, j = idx - c * MLPH;
    fc2_wT[idx] = f2bf(fc2_w[j * CC + c]);
  }
}

// ---------------- K0b: padded bias table biasTP[head][q:112][kv:128] ----------------
// kv pad (>=98): -30000 (kills pad cols in softmax); q pad rows: 0 (unused).
__global__ __launch_bounds__(256) void bias_kernel(const float* __restrict__ rpb,
                                                   float* __restrict__ biasTP) {
  int idx = blockIdx.x * 256 + threadIdx.x;
  if (idx >= NHEADS * 112 * 128) return;
  int head = idx / (112 * 128);
  int r = idx - head * 112 * 128;
  int q = r / 128, kv = r - q * 128;
  float v;
  if (kv >= NN) v = -30000.f;
  else if (q >= NN) v = 0.f;
  else {
    int itq = q / 49, rq = q - itq * 49, ihq = rq / 7, iwq = rq - ihq * 7;
    int itk = kv / 49, rk = kv - itk * 49, ihk = rk / 7, iwk = rk - ihk * 7;
    int ridx = (itq - itk + 1) * 169 + (ihq - ihk + 6) * 13 + (iwq - iwk + 6);
    v = rpb[ridx * NHEADS + head];
  }
  biasTP[idx] = v;
}

// ---------------- K0c: LN1 + shift-roll + window gather -> xnw[widx][112][96] bf16 ----------------
__global__ __launch_bounds__(256) void ln1_kernel(
    const float* __restrict__ x, const float* __restrict__ g1, const float* __restrict__ b1,
    u16* __restrict__ xnw)
{
  const int tid = threadIdx.x;
  const int row = blockIdx.x * 64 + (tid >> 2);   // 0 .. NWIN*112-1
  const int qd = tid & 3;                          // quarter: 24 channels
  const int widx = row / 112;
  const int n = row - widx * 112;
  u16* dst = xnw + (size_t)row * CC + qd * 24;
  if (n >= NN) {                                   // pad row -> zeros
    uint4 z = {0u, 0u, 0u, 0u};
    *(uint4*)(dst) = z; *(uint4*)(dst + 8) = z; *(uint4*)(dst + 16) = z;
    return;
  }
  int it = n / 49, r = n - it * 49, ih = r / 7, iw = r - ih * 7;
  int ww = widx & 15, hw = (widx >> 4) & 15, tw = widx >> 8;
  int t = tw * 2 + it + 1; if (t >= TT) t -= TT;
  int h = hw * 7 + ih + 3; if (h >= HH) h -= HH;
  int w = ww * 7 + iw + 3; if (w >= WD) w -= WD;
  const float* src = x + ((size_t)(t * HH + h) * WD + w) * CC + qd * 24;
  float v[24];
  #pragma unroll
  for (int i = 0; i < 24; i += 4) {
    float4 f = *(const float4*)(src + i);
    v[i] = f.x; v[i + 1] = f.y; v[i + 2] = f.z; v[i + 3] = f.w;
  }
  float sm = 0.f;
  #pragma unroll
  for (int i = 0; i < 24; ++i) sm += v[i];
  sm += __shfl_xor(sm, 1, 64);
  sm += __shfl_xor(sm, 2, 64);
  float mu = sm * (1.f / CC);
  float sq = 0.f;
  #pragma unroll
  for (int i = 0; i < 24; ++i) { float d = v[i] - mu; sq += d * d; }
  sq += __shfl_xor(sq, 1, 64);
  sq += __shfl_xor(sq, 2, 64);
  float inv = rsqrtf(sq * (1.f / CC) + 1e-5f);
  u16 o[24];
  #pragma unroll
  for (int i = 0; i < 24; ++i) {
    int c = qd * 24 + i;
    o[i] = f2bf((v[i] - mu) * inv * g1[c] + b1[c]);
  }
  *(uint4*)(dst)      = *(const uint4*)(o);
  *(uint4*)(dst + 8)  = *(const uint4*)(o + 8);
  *(uint4*)(dst + 16) = *(const uint4*)(o + 16);
}

// ---------------- K1: per-(window,head) QKV + attention (MFMA) ----------------
// bias folded into MFMA C-init (padded biasTP) + s_setprio around MFMA clusters.
__global__ __launch_bounds__(256, 4) void attn_kernel(
    const u16* __restrict__ xnw, const u16* __restrict__ qkv_wT, const float* __restrict__ qkv_b,
    const float* __restrict__ biasTP, u16* __restrict__ att)
{
  // union buffer: phases 1-2 -> sQ[112][40] + sK[112][40]; phases 3-4 -> sP[112][136]
  __shared__ __align__(16) u16 sUni[112 * SVP];   // 30464 B
  __shared__ __align__(16) u16 sVt[32 * SVP];     //  8704 B  [d][kv]
  __shared__ int sReg[112];

  u16* sQ = sUni;
  u16* sK = sUni + 112 * SQP;
  u16* sP = sUni;

  const int tid  = threadIdx.x;
  const int bid  = blockIdx.x;
  const int widx = bid / 3;
  const int head = bid - widx * 3;
  const int ww = widx & 15, hw = (widx >> 4) & 15, tw = widx >> 8;
  const bool bnd = (tw == 7) || (hw == 15) || (ww == 15);
  const int wid = tid >> 6;          // wave 0..3
  const int lane = tid & 63;
  const int g  = lane >> 4;          // lane group 0..3
  const int cl = lane & 15;          // col-in-tile
  const int mt1ok = (wid + 4) < 7;   // wave 3 has only one m-tile

  // ---- EARLY: prefetch phase-1 A-frags from global (consumed after phase-0 barrier)
  bf16x8 xa[2][3];
  {
    const u16* arow0 = xnw + ((size_t)widx * 112 + wid * 16 + cl) * CC + 8 * g;
    xa[0][0] = *(const bf16x8*)(arow0);
    xa[0][1] = *(const bf16x8*)(arow0 + 32);
    xa[0][2] = *(const bf16x8*)(arow0 + 64);
    const int mtb = mt1ok ? (wid + 4) : wid;
    const u16* arow1 = xnw + ((size_t)widx * 112 + mtb * 16 + cl) * CC + 8 * g;
    xa[1][0] = *(const bf16x8*)(arow1);
    xa[1][1] = *(const bf16x8*)(arow1 + 32);
    xa[1][2] = *(const bf16x8*)(arow1 + 64);
  }

  // ---- phase 0: zero sVt (pad kv cols must be 0) + region ids
  for (int i = tid; i < 32 * SVP / 2; i += 256) ((u32*)sVt)[i] = 0;
  if (tid < 112) {
    int n = tid;
    int reg = 0;
    if (n < NN) {
      int it = n / 49, r = n - it * 49, ih = r / 7, iw = r - ih * 7;
      int ts = tw * 2 + it, hs = hw * 7 + ih, ws2 = ww * 7 + iw;
      int rt = ts < TT - 2 ? 0 : (ts < TT - 1 ? 1 : 2);
      int rh = hs < HH - 7 ? 0 : (hs < HH - 3 ? 1 : 2);
      int rw = ws2 < WD - 7 ? 0 : (ws2 < WD - 3 ? 1 : 2);
      reg = rt * 9 + rh * 3 + rw;
    }
    sReg[n] = reg;
  }
  __syncthreads();

  // ---- phase 1: QKV slice (nt-outer: B loaded once, feeds both m-tiles)
  {
    const float scale = 0.17677669529663687f;   // 32^-0.5
    #pragma unroll
    for (int nt = 0; nt < 6; ++nt) {
      const int sec = nt >> 1;                      // 0=Q 1=K 2=V
      const int col = sec * 96 + head * 32 + (nt & 1) * 16 + cl;
      const u16* brow = qkv_wT + (size_t)col * CC + 8 * g;
      bf16x8 b0 = *(const bf16x8*)(brow);
      bf16x8 b1 = *(const bf16x8*)(brow + 32);
      bf16x8 b2 = *(const bf16x8*)(brow + 64);
      const float bias = qkv_b[col];
      #pragma unroll
      for (int mi = 0; mi < 2; ++mi) {
        const int mt = wid + mi * 4;
        if (mi == 1 && !mt1ok) continue;
        f32x4 acc = {0.f, 0.f, 0.f, 0.f};
        acc = MFMA16(xa[mi][0], b0, acc);
        acc = MFMA16(xa[mi][1], b1, acc);
        acc = MFMA16(xa[mi][2], b2, acc);
        #pragma unroll
        for (int r = 0; r < 4; ++r) {
          const int row = mt * 16 + 4 * g + r;
          const float v = acc[r] + bias;
          if (sec == 0)      sQ[row * SQP + (nt & 1) * 16 + cl] = f2bf(v * scale);
          else if (sec == 1) sK[row * SQP + (nt & 1) * 16 + cl] = f2bf(v);
          else               sVt[((nt & 1) * 16 + cl) * SVP + row] = f2bf(v);
        }
      }
    }
  }
  __syncthreads();

  // ---- phase 2: QK^T (bias in MFMA C-init) + mask + in-register softmax
  float sv[2][7][4];
  #pragma unroll
  for (int mi = 0; mi < 2; ++mi) {
    const int mt = wid + mi * 4;
    if (mt >= 7) continue;
    const int q0 = mt * 16 + 4 * g;
    bf16x8 a = *(const bf16x8*)&sQ[(mt * 16 + cl) * SQP + 8 * g];
    __builtin_amdgcn_s_setprio(1);
    #pragma unroll
    for (int nt = 0; nt < 7; ++nt) {
      bf16x8 b = *(const bf16x8*)&sK[(nt * 16 + cl) * SQP + 8 * g];
      const float* bp = biasTP + ((size_t)(head * 112 + q0) * 128 + nt * 16 + cl);
      f32x4 acc = {bp[0], bp[128], bp[256], bp[384]};
      acc = MFMA16(a, b, acc);
      #pragma unroll
      for (int r = 0; r < 4; ++r) sv[mi][nt][r] = acc[r];
    }
    __builtin_amdgcn_s_setprio(0);
    if (bnd) {
      #pragma unroll
      for (int nt = 0; nt < 7; ++nt) {
        const int kv = nt * 16 + cl;
        #pragma unroll
        for (int r = 0; r < 4; ++r) {
          if (sReg[q0 + r] != sReg[kv]) sv[mi][nt][r] -= 100.f;
        }
      }
    }
    #pragma unroll
    for (int r = 0; r < 4; ++r) {
      float mx = sv[mi][0][r];
      #pragma unroll
      for (int nt = 1; nt < 7; ++nt) mx = fmaxf(mx, sv[mi][nt][r]);
      #pragma unroll
      for (int d = 1; d < 16; d <<= 1) mx = fmaxf(mx, __shfl_xor(mx, d, 64));
      float sm = 0.f;
      #pragma unroll
      for (int nt = 0; nt < 7; ++nt) { float p = __expf(sv[mi][nt][r] - mx); sv[mi][nt][r] = p; sm += p; }
      #pragma unroll
      for (int d = 1; d < 16; d <<= 1) sm += __shfl_xor(sm, d, 64);
      const float inv = 1.f / sm;
      #pragma unroll
      for (int nt = 0; nt < 7; ++nt) sv[mi][nt][r] *= inv;
    }
  }
  __syncthreads();   // all Q/K reads complete before P overwrites the union buffer

  // ---- phase 3: write P (bf16) + zero pad cols 112..127
  #pragma unroll
  for (int mi = 0; mi < 2; ++mi) {
    const int mt = wid + mi * 4;
    if (mt >= 7) continue;
    #pragma unroll
    for (int r = 0; r < 4; ++r) {
      const int q = mt * 16 + 4 * g + r;
      u16* prow = &sP[q * SVP];
      #pragma unroll
      for (int nt = 0; nt < 7; ++nt) prow[nt * 16 + cl] = f2bf(sv[mi][nt][r]);
      prow[112 + cl] = 0;
    }
  }
  __syncthreads();

  // ---- phase 4: PV (MFMA, K=128) + store
  for (int t = wid; t < 14; t += 4) {
    const int mt = t >> 1, ntd = t & 1;
    f32x4 acc = {0.f, 0.f, 0.f, 0.f};
    __builtin_amdgcn_s_setprio(1);
    #pragma unroll
    for (int ks = 0; ks < 4; ++ks) {
      bf16x8 a = *(const bf16x8*)&sP[(mt * 16 + cl) * SVP + ks * 32 + 8 * g];
      bf16x8 b = *(const bf16x8*)&sVt[(ntd * 16 + cl) * SVP + ks * 32 + 8 * g];
      acc = MFMA16(a, b, acc);
    }
    __builtin_amdgcn_s_setprio(0);
    #pragma unroll
    for (int r = 0; r < 4; ++r) {
      const int q = mt * 16 + 4 * g + r;
      if (q < NN)
        att[((size_t)widx * NN + q) * CC + head * 32 + ntd * 16 + cl] = f2bf(acc[r]);
    }
  }
}

// ---------------- K2: fused proj + residual + LN2 + FC1 + GELU + FC2 + residual ----------------
// 2x B-reuse + 25.9KB LDS (6 blocks/CU). (128,4): the only proven no-spill bound.
// FC2 A-banks kept at a[2][3] (96-wide k-chunks) to bound register pressure.
__global__ __launch_bounds__(128, 4) void pm_kernel(
    const u16* __restrict__ att, const u16* __restrict__ proj_wT, const float* __restrict__ proj_b,
    const float* __restrict__ x,
    const float* __restrict__ g2, const float* __restrict__ b2,
    const u16* __restrict__ fc1_wT, const float* __restrict__ fc1_b,
    const u16* __restrict__ fc2_wT, const float* __restrict__ fc2_b,
    float* __restrict__ out)
{
  __shared__ __align__(16) u16 sHh[32 * SH2P];   // 12800 B (H half: 192 cols)
  __shared__ __align__(16) u16 sX1[32 * SX1P];   //  6400 B
  __shared__ __align__(16) u16 sXn[32 * SXP];    //  6656 B
  // total 25856 B -> 6 blocks/CU (12 waves)

  const int tid  = threadIdx.x;
  const int base = blockIdx.x * 32;              // window-token base
  const int hnt  = tid >> 6;        // wave = nt-half (0..1)
  const int lane = tid & 63, g = lane >> 4, cl = lane & 15;

  // ---- P-1: natural-row indices (both m-tiles) + EARLY x-residual prefetch
  u32 nr[2][4];
  #pragma unroll
  for (int mt = 0; mt < 2; ++mt) {
    #pragma unroll
    for (int r = 0; r < 4; ++r) {
      int tok = base + mt * 16 + 4 * g + r;
      int widx = tok / NN, n = tok - widx * NN;
      int ww = widx & 15, hw = (widx >> 4) & 15, tw = widx >> 8;
      int it = n / 49, rr = n - it * 49, ih = rr / 7, iw = rr - ih * 7;
      int t = tw * 2 + it + 1; if (t >= TT) t -= TT;
      int h = hw * 7 + ih + 3; if (h >= HH) h -= HH;
      int w = ww * 7 + iw + 3; if (w >= WD) w -= WD;
      nr[mt][r] = (u32)((t * HH + h) * WD + w);
    }
  }
  float xres[3][2][4];
  #pragma unroll
  for (int j = 0; j < 3; ++j) {
    const int col = (hnt * 3 + j) * 16 + cl;
    #pragma unroll
    for (int mt = 0; mt < 2; ++mt)
      #pragma unroll
      for (int r = 0; r < 4; ++r)
        xres[j][mt][r] = x[(size_t)nr[mt][r] * CC + col];
  }

  // ---- P1: proj GEMM [32x96]@[96x96]; A direct from global att (contiguous rows);
  // B loaded once per nt, used for BOTH m-tiles
  float x1v[3][2][4];
  {
    bf16x8 a[2][3];
    #pragma unroll
    for (int mt = 0; mt < 2; ++mt) {
      const u16* aRow = att + (size_t)(base + mt * 16 + cl) * CC + 8 * g;
      a[mt][0] = *(const bf16x8*)(aRow);
      a[mt][1] = *(const bf16x8*)(aRow + 32);
      a[mt][2] = *(const bf16x8*)(aRow + 64);
    }
    #pragma unroll
    for (int j = 0; j < 3; ++j) {
      const int nt = hnt * 3 + j;
      const u16* bRow = proj_wT + (nt * 16 + cl) * CC + 8 * g;
      bf16x8 b0 = *(const bf16x8*)(bRow);
      bf16x8 b1 = *(const bf16x8*)(bRow + 32);
      bf16x8 b2 = *(const bf16x8*)(bRow + 64);
      const float bc = proj_b[nt * 16 + cl];
      #pragma unroll
      for (int mt = 0; mt < 2; ++mt) {
        f32x4 acc = {0.f, 0.f, 0.f, 0.f};
        acc = MFMA16(a[mt][0], b0, acc);
        acc = MFMA16(a[mt][1], b1, acc);
        acc = MFMA16(a[mt][2], b2, acc);
        #pragma unroll
        for (int r = 0; r < 4; ++r) {
          const int row = mt * 16 + 4 * g + r;
          const float v = acc[r] + bc + xres[j][mt][r];
          x1v[j][mt][r] = v;
          sX1[row * SX1P + nt * 16 + cl] = f2bf(v);
        }
      }
    }
  }
  __syncthreads();

  // ---- P2: LN2 from sX1 (bf16): token = tid>>2 (32), sub = tid&3 (24 ch); 4-lane shfl
  {
    const int tok = tid >> 2, sub = tid & 3;
    const u16* p = &sX1[tok * SX1P + sub * 24];
    float v[24];
    #pragma unroll
    for (int k = 0; k < 12; ++k) {
      u32 u = *(const u32*)(p + 2 * k);
      v[2 * k] = bflo(u); v[2 * k + 1] = bfhi(u);
    }
    float sm = 0.f;
    #pragma unroll
    for (int i = 0; i < 24; ++i) sm += v[i];
    sm += __shfl_xor(sm, 1, 64);
    sm += __shfl_xor(sm, 2, 64);
    float mu = sm * (1.f / CC);
    float sq = 0.f;
    #pragma unroll
    for (int i = 0; i < 24; ++i) { float d = v[i] - mu; sq += d * d; }
    sq += __shfl_xor(sq, 1, 64);
    sq += __shfl_xor(sq, 2, 64);
    float inv = rsqrtf(sq * (1.f / CC) + 1e-5f);
    u16 o[24];
    #pragma unroll
    for (int i = 0; i < 24; ++i) {
      int c = sub * 24 + i;
      o[i] = f2bf((v[i] - mu) * inv * g2[c] + b2[c]);
    }
    u16* dst = &sXn[tok * SXP + sub * 24];
    *(uint4*)(dst)      = *(const uint4*)(o);
    *(uint4*)(dst + 8)  = *(const uint4*)(o + 8);
    *(uint4*)(dst + 16) = *(const uint4*)(o + 16);
  }
  __syncthreads();

  // ---- P3/P4: FC1(+GELU) and FC2 in two 192-col halves through sHh
  f32x4 acc2[3][2];
  #pragma unroll
  for (int j = 0; j < 3; ++j)
    #pragma unroll
    for (int mt = 0; mt < 2; ++mt) { f32x4 z = {0.f, 0.f, 0.f, 0.f}; acc2[j][mt] = z; }

  bf16x8 aXn[2][3];
  #pragma unroll
  for (int mt = 0; mt < 2; ++mt) {
    const u16* ap = &sXn[(mt * 16 + cl) * SXP + 8 * g];
    aXn[mt][0] = *(const bf16x8*)(ap);
    aXn[mt][1] = *(const bf16x8*)(ap + 32);
    aXn[mt][2] = *(const bf16x8*)(ap + 64);
  }

  #pragma unroll
  for (int hf = 0; hf < 2; ++hf) {
    // FC1 half: 6 nt per wave (B once -> 2 m-tiles), prefetch 1 ahead
    {
      const int nt0 = hf * 12 + hnt * 6;
      const u16* bPtr = fc1_wT + ((size_t)(nt0 * 16 + cl)) * CC + 8 * g;
      bf16x8 b0 = *(const bf16x8*)(bPtr);
      bf16x8 b1 = *(const bf16x8*)(bPtr + 32);
      bf16x8 b2 = *(const bf16x8*)(bPtr + 64);
      #pragma unroll
      for (int j = 0; j < 6; ++j) {
        bf16x8 c0 = b0, c1 = b1, c2 = b2;
        if (j < 5) {
          bPtr += 16 * CC;
          b0 = *(const bf16x8*)(bPtr);
          b1 = *(const bf16x8*)(bPtr + 32);
          b2 = *(const bf16x8*)(bPtr + 64);
        }
        const int nt = nt0 + j;
        const float bj = fc1_b[nt * 16 + cl];
        const int lcol = (hnt * 6 + j) * 16 + cl;       // 0..191 within this half
        #pragma unroll
        for (int mt = 0; mt < 2; ++mt) {
          f32x4 acc = {0.f, 0.f, 0.f, 0.f};
          acc = MFMA16(aXn[mt][0], c0, acc);
          acc = MFMA16(aXn[mt][1], c1, acc);
          acc = MFMA16(aXn[mt][2], c2, acc);
          #pragma unroll
          for (int r = 0; r < 4; ++r) {
            float v = acc[r] + bj;
            // tanh-GELU: v*e/(e+1), e = exp(v*(1.59576912 + 0.07135481*v^2))
            float p2 = v * v;
            float aa = v * fmaf(0.07135481f, p2, 1.59576912f);
            float e  = __expf(aa);
            float gl = v * e * __builtin_amdgcn_rcpf(e + 1.f);
            sHh[(mt * 16 + 4 * g + r) * SH2P + lcol] = f2bf(gl);
          }
        }
      }
    }
    __syncthreads();
    // FC2 partial (k-slice hf*192..+192) in two 96-wide chunks (a[2][3] banks)
    #pragma unroll
    for (int c2 = 0; c2 < 2; ++c2) {
      bf16x8 a[2][3];
      #pragma unroll
      for (int mt = 0; mt < 2; ++mt) {
        const u16* aBase = &sHh[(mt * 16 + cl) * SH2P + c2 * 96 + 8 * g];
        a[mt][0] = *(const bf16x8*)(aBase);
        a[mt][1] = *(const bf16x8*)(aBase + 32);
        a[mt][2] = *(const bf16x8*)(aBase + 64);
      }
      #pragma unroll
      for (int j = 0; j < 3; ++j) {
        const int nt = hnt * 3 + j;
        const u16* bBase = fc2_wT + (size_t)(nt * 16 + cl) * MLPH + hf * 192 + c2 * 96 + 8 * g;
        bf16x8 b0 = *(const bf16x8*)(bBase);
        bf16x8 b1 = *(const bf16x8*)(bBase + 32);
        bf16x8 b2 = *(const bf16x8*)(bBase + 64);
        #pragma unroll
        for (int mt = 0; mt < 2; ++mt) {
          acc2[j][mt] = MFMA16(a[mt][0], b0, acc2[j][mt]);
          acc2[j][mt] = MFMA16(a[mt][1], b1, acc2[j][mt]);
          acc2[j][mt] = MFMA16(a[mt][2], b2, acc2[j][mt]);
        }
      }
    }
    if (hf == 0) __syncthreads();   // sHh reads done before half-1 FC1 overwrites
  }

  // ---- epilogue: out = x1(reg) + fc2_b + acc2
  #pragma unroll
  for (int j = 0; j < 3; ++j) {
    const int nt = hnt * 3 + j;
    const float bc = fc2_b[nt * 16 + cl];
    #pragma unroll
    for (int mt = 0; mt < 2; ++mt)
      #pragma unroll
      for (int r = 0; r < 4; ++r)
        out[(size_t)nr[mt][r] * CC + nt * 16 + cl] = x1v[j][mt][r] + acc2[j][mt][r] + bc;
  }
}

extern "C" void kernel_launch(void* const* d_in, const int* in_sizes, int n_in,
                              void* d_out, int out_size, void* d_ws, size_t ws_size,
                              hipStream_t stream) {
  const float* x      = (const float*)d_in[0];
  const float* g1     = (const float*)d_in[1];
  const float* b1     = (const float*)d_in[2];
  const float* qkv_w  = (const float*)d_in[3];
  const float* qkv_b  = (const float*)d_in[4];
  const float* rpb    = (const float*)d_in[5];
  const float* proj_w = (const float*)d_in[6];
  const float* proj_b = (const float*)d_in[7];
  const float* g2     = (const float*)d_in[8];
  const float* b2     = (const float*)d_in[9];
  const float* fc1_w  = (const float*)d_in[10];
  const float* fc1_b  = (const float*)d_in[11];
  const float* fc2_w  = (const float*)d_in[12];
  const float* fc2_b  = (const float*)d_in[13];

  char* ws = (char*)d_ws;
  u16*   att    = (u16*)ws;                                   // NTOK*96 bf16 = 38.5 MB
  u16*   xnw    = (u16*)(ws + (size_t)NTOK * CC * 2);         // NWIN*112*96 bf16 = 44 MB
  char*  wtail  = ws + (size_t)NTOK * CC * 2 + (size_t)NWIN * 112 * CC * 2;
  float* biasTP = (float*)wtail;                              // 3*112*128*4 = 172032 B
  u16*   qkv_wT = (u16*)(wtail + 172032);                     // 55296 B
  u16*   proj_wT= (u16*)(wtail + 172032 + 55296);             // 18432 B
  u16*   fc1_wT = (u16*)(wtail + 172032 + 55296 + 18432);     // 73728 B
  u16*   fc2_wT = (u16*)(wtail + 172032 + 55296 + 18432 + 73728); // 73728 B

  wprep_kernel<<<(27648 + 9216 + 36864 + 36864 + 255) / 256, 256, 0, stream>>>(
      qkv_w, proj_w, fc1_w, fc2_w, qkv_wT, proj_wT, fc1_wT, fc2_wT);
  bias_kernel<<<(NHEADS * 112 * 128 + 255) / 256, 256, 0, stream>>>(rpb, biasTP);
  ln1_kernel<<<NWIN * 112 / 64, 256, 0, stream>>>(x, g1, b1, xnw);
  attn_kernel<<<NWIN * NHEADS, 256, 0, stream>>>(xnw, qkv_wT, qkv_b, biasTP, att);
  pm_kernel<<<NTOK / 32, 128, 0, stream>>>(att, proj_wT, proj_b, x, g2, b2,
                                           fc1_wT, fc1_b, fc2_wT, fc2_b, (float*)d_out);
}

// Round 21
// 210.742 us; speedup vs baseline: 1.1848x; 1.0352x over previous
//
#include <hip/hip_runtime.h>
#include <math.h>

#define TT 16
#define HH 112
#define WD 112
#define CC 96
#define NHEADS 3
#define HD 32
#define NN 98          // window tokens 2*7*7
#define NWIN 2048      // 8*16*16
#define NTOK 200704    // T*H*W == NWIN*NN
#define MLPH 384
#define SXP 104        // row stride (bf16) LDS tiles (208B rows, 16B aligned)
#define SQP 40         // row stride (bf16) per-head sQ/sK
#define SVP 136        // row stride (bf16) sVt/sP
#define SHP 392        // row stride (bf16) sH full (384 cols + 8 pad)
#define SX1P 100       // row stride (bf16) sX1

typedef unsigned int  u32;
typedef unsigned short u16;
typedef float f32x4 __attribute__((ext_vector_type(4)));
typedef short bf16x8 __attribute__((ext_vector_type(8)));

__device__ inline u16 f2bf(float f) {
  u32 u = __float_as_uint(f);
  u += 0x7fffu + ((u >> 16) & 1u);
  return (u16)(u >> 16);
}
__device__ inline float bflo(u32 u) { return __uint_as_float(u << 16); }
__device__ inline float bfhi(u32 u) { return __uint_as_float(u & 0xffff0000u); }

#define MFMA16(a, b, c) __builtin_amdgcn_mfma_f32_16x16x32_bf16((a), (b), (c), 0, 0, 0)

// ---------------- K0a: transpose all weights to bf16 col-major ----------------
__global__ __launch_bounds__(256) void wprep_kernel(
    const float* __restrict__ qkv_w, const float* __restrict__ proj_w,
    const float* __restrict__ fc1_w, const float* __restrict__ fc2_w,
    u16* __restrict__ qkv_wT, u16* __restrict__ proj_wT,
    u16* __restrict__ fc1_wT, u16* __restrict__ fc2_wT) {
  int idx = blockIdx.x * 256 + threadIdx.x;
  if (idx < 27648) {                       // qkv_wT[col][c]
    int col = idx / CC, c = idx - col * CC;
    qkv_wT[idx] = f2bf(qkv_w[c * (3 * CC) + col]);
    return;
  }
  idx -= 27648;
  if (idx < 9216) {                        // proj_wT[col][c]
    int col = idx / CC, c = idx - col * CC;
    proj_wT[idx] = f2bf(proj_w[c * CC + col]);
    return;
  }
  idx -= 9216;
  if (idx < 36864) {                       // fc1_wT[j][c]
    int j = idx / CC, c = idx - j * CC;
    fc1_wT[idx] = f2bf(fc1_w[c * MLPH + j]);
    return;
  }
  idx -= 36864;
  if (idx < 36864) {                       // fc2_wT[c][j]
    int c = idx / MLPH, j = idx - c * MLPH;
    fc2_wT[idx] = f2bf(fc2_w[j * CC + c]);
  }
}

// ---------------- K0b: padded bias table biasTP[head][q:112][kv:128] ----------------
// kv pad (>=98): -30000 (kills pad cols in softmax); q pad rows: 0 (unused).
__global__ __launch_bounds__(256) void bias_kernel(const float* __restrict__ rpb,
                                                   float* __restrict__ biasTP) {
  int idx = blockIdx.x * 256 + threadIdx.x;
  if (idx >= NHEADS * 112 * 128) return;
  int head = idx / (112 * 128);
  int r = idx - head * 112 * 128;
  int q = r / 128, kv = r - q * 128;
  float v;
  if (kv >= NN) v = -30000.f;
  else if (q >= NN) v = 0.f;
  else {
    int itq = q / 49, rq = q - itq * 49, ihq = rq / 7, iwq = rq - ihq * 7;
    int itk = kv / 49, rk = kv - itk * 49, ihk = rk / 7, iwk = rk - ihk * 7;
    int ridx = (itq - itk + 1) * 169 + (ihq - ihk + 6) * 13 + (iwq - iwk + 6);
    v = rpb[ridx * NHEADS + head];
  }
  biasTP[idx] = v;
}

// ---------------- K0c: LN1 + shift-roll + window gather -> xnw[widx][112][96] bf16 ----------------
__global__ __launch_bounds__(256) void ln1_kernel(
    const float* __restrict__ x, const float* __restrict__ g1, const float* __restrict__ b1,
    u16* __restrict__ xnw)
{
  const int tid = threadIdx.x;
  const int row = blockIdx.x * 64 + (tid >> 2);   // 0 .. NWIN*112-1
  const int qd = tid & 3;                          // quarter: 24 channels
  const int widx = row / 112;
  const int n = row - widx * 112;
  u16* dst = xnw + (size_t)row * CC + qd * 24;
  if (n >= NN) {                                   // pad row -> zeros
    uint4 z = {0u, 0u, 0u, 0u};
    *(uint4*)(dst) = z; *(uint4*)(dst + 8) = z; *(uint4*)(dst + 16) = z;
    return;
  }
  int it = n / 49, r = n - it * 49, ih = r / 7, iw = r - ih * 7;
  int ww = widx & 15, hw = (widx >> 4) & 15, tw = widx >> 8;
  int t = tw * 2 + it + 1; if (t >= TT) t -= TT;
  int h = hw * 7 + ih + 3; if (h >= HH) h -= HH;
  int w = ww * 7 + iw + 3; if (w >= WD) w -= WD;
  const float* src = x + ((size_t)(t * HH + h) * WD + w) * CC + qd * 24;
  float v[24];
  #pragma unroll
  for (int i = 0; i < 24; i += 4) {
    float4 f = *(const float4*)(src + i);
    v[i] = f.x; v[i + 1] = f.y; v[i + 2] = f.z; v[i + 3] = f.w;
  }
  float sm = 0.f;
  #pragma unroll
  for (int i = 0; i < 24; ++i) sm += v[i];
  sm += __shfl_xor(sm, 1, 64);
  sm += __shfl_xor(sm, 2, 64);
  float mu = sm * (1.f / CC);
  float sq = 0.f;
  #pragma unroll
  for (int i = 0; i < 24; ++i) { float d = v[i] - mu; sq += d * d; }
  sq += __shfl_xor(sq, 1, 64);
  sq += __shfl_xor(sq, 2, 64);
  float inv = rsqrtf(sq * (1.f / CC) + 1e-5f);
  u16 o[24];
  #pragma unroll
  for (int i = 0; i < 24; ++i) {
    int c = qd * 24 + i;
    o[i] = f2bf((v[i] - mu) * inv * g1[c] + b1[c]);
  }
  *(uint4*)(dst)      = *(const uint4*)(o);
  *(uint4*)(dst + 8)  = *(const uint4*)(o + 8);
  *(uint4*)(dst + 16) = *(const uint4*)(o + 16);
}

// ---------------- K1: per-(window,head) QKV + attention (MFMA) ----------------
// bias folded into MFMA C-init (padded biasTP) + s_setprio around MFMA clusters.
__global__ __launch_bounds__(256, 4) void attn_kernel(
    const u16* __restrict__ xnw, const u16* __restrict__ qkv_wT, const float* __restrict__ qkv_b,
    const float* __restrict__ biasTP, u16* __restrict__ att)
{
  // union buffer: phases 1-2 -> sQ[112][40] + sK[112][40]; phases 3-4 -> sP[112][136]
  __shared__ __align__(16) u16 sUni[112 * SVP];   // 30464 B
  __shared__ __align__(16) u16 sVt[32 * SVP];     //  8704 B  [d][kv]
  __shared__ int sReg[112];

  u16* sQ = sUni;
  u16* sK = sUni + 112 * SQP;
  u16* sP = sUni;

  const int tid  = threadIdx.x;
  const int bid  = blockIdx.x;
  const int widx = bid / 3;
  const int head = bid - widx * 3;
  const int ww = widx & 15, hw = (widx >> 4) & 15, tw = widx >> 8;
  const bool bnd = (tw == 7) || (hw == 15) || (ww == 15);
  const int wid = tid >> 6;          // wave 0..3
  const int lane = tid & 63;
  const int g  = lane >> 4;          // lane group 0..3
  const int cl = lane & 15;          // col-in-tile
  const int mt1ok = (wid + 4) < 7;   // wave 3 has only one m-tile

  // ---- EARLY: prefetch phase-1 A-frags from global (consumed after phase-0 barrier)
  bf16x8 xa[2][3];
  {
    const u16* arow0 = xnw + ((size_t)widx * 112 + wid * 16 + cl) * CC + 8 * g;
    xa[0][0] = *(const bf16x8*)(arow0);
    xa[0][1] = *(const bf16x8*)(arow0 + 32);
    xa[0][2] = *(const bf16x8*)(arow0 + 64);
    const int mtb = mt1ok ? (wid + 4) : wid;
    const u16* arow1 = xnw + ((size_t)widx * 112 + mtb * 16 + cl) * CC + 8 * g;
    xa[1][0] = *(const bf16x8*)(arow1);
    xa[1][1] = *(const bf16x8*)(arow1 + 32);
    xa[1][2] = *(const bf16x8*)(arow1 + 64);
  }

  // ---- phase 0: zero sVt (pad kv cols must be 0) + region ids
  for (int i = tid; i < 32 * SVP / 2; i += 256) ((u32*)sVt)[i] = 0;
  if (tid < 112) {
    int n = tid;
    int reg = 0;
    if (n < NN) {
      int it = n / 49, r = n - it * 49, ih = r / 7, iw = r - ih * 7;
      int ts = tw * 2 + it, hs = hw * 7 + ih, ws2 = ww * 7 + iw;
      int rt = ts < TT - 2 ? 0 : (ts < TT - 1 ? 1 : 2);
      int rh = hs < HH - 7 ? 0 : (hs < HH - 3 ? 1 : 2);
      int rw = ws2 < WD - 7 ? 0 : (ws2 < WD - 3 ? 1 : 2);
      reg = rt * 9 + rh * 3 + rw;
    }
    sReg[n] = reg;
  }
  __syncthreads();

  // ---- phase 1: QKV slice (nt-outer: B loaded once, feeds both m-tiles)
  {
    const float scale = 0.17677669529663687f;   // 32^-0.5
    #pragma unroll
    for (int nt = 0; nt < 6; ++nt) {
      const int sec = nt >> 1;                      // 0=Q 1=K 2=V
      const int col = sec * 96 + head * 32 + (nt & 1) * 16 + cl;
      const u16* brow = qkv_wT + (size_t)col * CC + 8 * g;
      bf16x8 b0 = *(const bf16x8*)(brow);
      bf16x8 b1 = *(const bf16x8*)(brow + 32);
      bf16x8 b2 = *(const bf16x8*)(brow + 64);
      const float bias = qkv_b[col];
      #pragma unroll
      for (int mi = 0; mi < 2; ++mi) {
        const int mt = wid + mi * 4;
        if (mi == 1 && !mt1ok) continue;
        f32x4 acc = {0.f, 0.f, 0.f, 0.f};
        acc = MFMA16(xa[mi][0], b0, acc);
        acc = MFMA16(xa[mi][1], b1, acc);
        acc = MFMA16(xa[mi][2], b2, acc);
        #pragma unroll
        for (int r = 0; r < 4; ++r) {
          const int row = mt * 16 + 4 * g + r;
          const float v = acc[r] + bias;
          if (sec == 0)      sQ[row * SQP + (nt & 1) * 16 + cl] = f2bf(v * scale);
          else if (sec == 1) sK[row * SQP + (nt & 1) * 16 + cl] = f2bf(v);
          else               sVt[((nt & 1) * 16 + cl) * SVP + row] = f2bf(v);
        }
      }
    }
  }
  __syncthreads();

  // ---- phase 2: QK^T (bias in MFMA C-init) + mask + in-register softmax
  float sv[2][7][4];
  #pragma unroll
  for (int mi = 0; mi < 2; ++mi) {
    const int mt = wid + mi * 4;
    if (mt >= 7) continue;
    const int q0 = mt * 16 + 4 * g;
    bf16x8 a = *(const bf16x8*)&sQ[(mt * 16 + cl) * SQP + 8 * g];
    __builtin_amdgcn_s_setprio(1);
    #pragma unroll
    for (int nt = 0; nt < 7; ++nt) {
      bf16x8 b = *(const bf16x8*)&sK[(nt * 16 + cl) * SQP + 8 * g];
      const float* bp = biasTP + ((size_t)(head * 112 + q0) * 128 + nt * 16 + cl);
      f32x4 acc = {bp[0], bp[128], bp[256], bp[384]};
      acc = MFMA16(a, b, acc);
      #pragma unroll
      for (int r = 0; r < 4; ++r) sv[mi][nt][r] = acc[r];
    }
    __builtin_amdgcn_s_setprio(0);
    if (bnd) {
      #pragma unroll
      for (int nt = 0; nt < 7; ++nt) {
        const int kv = nt * 16 + cl;
        #pragma unroll
        for (int r = 0; r < 4; ++r) {
          if (sReg[q0 + r] != sReg[kv]) sv[mi][nt][r] -= 100.f;
        }
      }
    }
    #pragma unroll
    for (int r = 0; r < 4; ++r) {
      float mx = sv[mi][0][r];
      #pragma unroll
      for (int nt = 1; nt < 7; ++nt) mx = fmaxf(mx, sv[mi][nt][r]);
      #pragma unroll
      for (int d = 1; d < 16; d <<= 1) mx = fmaxf(mx, __shfl_xor(mx, d, 64));
      float sm = 0.f;
      #pragma unroll
      for (int nt = 0; nt < 7; ++nt) { float p = __expf(sv[mi][nt][r] - mx); sv[mi][nt][r] = p; sm += p; }
      #pragma unroll
      for (int d = 1; d < 16; d <<= 1) sm += __shfl_xor(sm, d, 64);
      const float inv = 1.f / sm;
      #pragma unroll
      for (int nt = 0; nt < 7; ++nt) sv[mi][nt][r] *= inv;
    }
  }
  __syncthreads();   // all Q/K reads complete before P overwrites the union buffer

  // ---- phase 3: write P (bf16) + zero pad cols 112..127
  #pragma unroll
  for (int mi = 0; mi < 2; ++mi) {
    const int mt = wid + mi * 4;
    if (mt >= 7) continue;
    #pragma unroll
    for (int r = 0; r < 4; ++r) {
      const int q = mt * 16 + 4 * g + r;
      u16* prow = &sP[q * SVP];
      #pragma unroll
      for (int nt = 0; nt < 7; ++nt) prow[nt * 16 + cl] = f2bf(sv[mi][nt][r]);
      prow[112 + cl] = 0;
    }
  }
  __syncthreads();

  // ---- phase 4: PV (MFMA, K=128) + store
  for (int t = wid; t < 14; t += 4) {
    const int mt = t >> 1, ntd = t & 1;
    f32x4 acc = {0.f, 0.f, 0.f, 0.f};
    __builtin_amdgcn_s_setprio(1);
    #pragma unroll
    for (int ks = 0; ks < 4; ++ks) {
      bf16x8 a = *(const bf16x8*)&sP[(mt * 16 + cl) * SVP + ks * 32 + 8 * g];
      bf16x8 b = *(const bf16x8*)&sVt[(ntd * 16 + cl) * SVP + ks * 32 + 8 * g];
      acc = MFMA16(a, b, acc);
    }
    __builtin_amdgcn_s_setprio(0);
    #pragma unroll
    for (int r = 0; r < 4; ++r) {
      const int q = mt * 16 + 4 * g + r;
      if (q < NN)
        att[((size_t)widx * NN + q) * CC + head * 32 + ntd * 16 + cl] = f2bf(acc[r]);
    }
  }
}

// ---------------- K2: fused proj + residual + LN2 + FC1 + GELU + FC2 + residual ----------------
// r18-measured best (147us): 2x B-reuse, 128 thr / 2 waves per 32-token block,
// sH full-width with sA/sX1 aliased inside, FC2 in 4 k-quarters, (128,4) no-spill.
__global__ __launch_bounds__(128, 4) void pm_kernel(
    const u16* __restrict__ att, const u16* __restrict__ proj_wT, const float* __restrict__ proj_b,
    const float* __restrict__ x,
    const float* __restrict__ g2, const float* __restrict__ b2,
    const u16* __restrict__ fc1_wT, const float* __restrict__ fc1_b,
    const u16* __restrict__ fc2_wT, const float* __restrict__ fc2_b,
    float* __restrict__ out)
{
  __shared__ __align__(16) u16 sH [32 * SHP];    // 25088 B (sA and sX1 alias inside)
  __shared__ __align__(16) u16 sXn[32 * SXP];    //  6656 B

  u16* sA  = sH;          // [32][SXP] attention-output tile
  u16* sX1 = sH + 4096;   // [32][SX1P] x1 bf16 for LN2

  const int tid  = threadIdx.x;
  const int base = blockIdx.x * 32;              // window-token base
  const int hnt  = tid >> 6;        // wave = nt-half (0..1)
  const int lane = tid & 63, g = lane >> 4, cl = lane & 15;

  // ---- P-1: natural-row indices (both m-tiles) + EARLY x-residual prefetch
  u32 nr[2][4];
  #pragma unroll
  for (int mt = 0; mt < 2; ++mt) {
    #pragma unroll
    for (int r = 0; r < 4; ++r) {
      int tok = base + mt * 16 + 4 * g + r;
      int widx = tok / NN, n = tok - widx * NN;
      int ww = widx & 15, hw = (widx >> 4) & 15, tw = widx >> 8;
      int it = n / 49, rr = n - it * 49, ih = rr / 7, iw = rr - ih * 7;
      int t = tw * 2 + it + 1; if (t >= TT) t -= TT;
      int h = hw * 7 + ih + 3; if (h >= HH) h -= HH;
      int w = ww * 7 + iw + 3; if (w >= WD) w -= WD;
      nr[mt][r] = (u32)((t * HH + h) * WD + w);
    }
  }
  float xres[3][2][4];
  #pragma unroll
  for (int j = 0; j < 3; ++j) {
    const int col = (hnt * 3 + j) * 16 + cl;
    #pragma unroll
    for (int mt = 0; mt < 2; ++mt)
      #pragma unroll
      for (int r = 0; r < 4; ++r)
        xres[j][mt][r] = x[(size_t)nr[mt][r] * CC + col];
  }

  // ---- P0: att tile load -> sA (128 threads, 384 uint4)
  for (int e = tid; e < 32 * 12; e += 128) {
    int tok = e / 12, kb = e - tok * 12;
    *(uint4*)&sA[tok * SXP + kb * 8] =
        ((const uint4*)att)[(size_t)(base + tok) * 12 + kb];
  }
  __syncthreads();

  // ---- P1: proj GEMM [32x96]@[96x96]: B loaded once per nt, used for BOTH m-tiles
  float x1v[3][2][4];
  {
    bf16x8 a[2][3];
    #pragma unroll
    for (int mt = 0; mt < 2; ++mt) {
      const u16* aRow = &sA[(mt * 16 + cl) * SXP + 8 * g];
      a[mt][0] = *(const bf16x8*)(aRow);
      a[mt][1] = *(const bf16x8*)(aRow + 32);
      a[mt][2] = *(const bf16x8*)(aRow + 64);
    }
    #pragma unroll
    for (int j = 0; j < 3; ++j) {
      const int nt = hnt * 3 + j;
      const u16* bRow = proj_wT + (nt * 16 + cl) * CC + 8 * g;
      bf16x8 b0 = *(const bf16x8*)(bRow);
      bf16x8 b1 = *(const bf16x8*)(bRow + 32);
      bf16x8 b2 = *(const bf16x8*)(bRow + 64);
      const float bc = proj_b[nt * 16 + cl];
      #pragma unroll
      for (int mt = 0; mt < 2; ++mt) {
        f32x4 acc = {0.f, 0.f, 0.f, 0.f};
        acc = MFMA16(a[mt][0], b0, acc);
        acc = MFMA16(a[mt][1], b1, acc);
        acc = MFMA16(a[mt][2], b2, acc);
        #pragma unroll
        for (int r = 0; r < 4; ++r) {
          const int row = mt * 16 + 4 * g + r;
          const float v = acc[r] + bc + xres[j][mt][r];
          x1v[j][mt][r] = v;
          sX1[row * SX1P + nt * 16 + cl] = f2bf(v);
        }
      }
    }
  }
  __syncthreads();   // sA reads + sX1 writes complete

  // ---- P2: LN2 from sX1 (bf16): token = tid>>2 (32), sub = tid&3 (24 ch); 4-lane shfl
  {
    const int tok = tid >> 2, sub = tid & 3;
    const u16* p = &sX1[tok * SX1P + sub * 24];
    float v[24];
    #pragma unroll
    for (int k = 0; k < 12; ++k) {
      u32 u = *(const u32*)(p + 2 * k);
      v[2 * k] = bflo(u); v[2 * k + 1] = bfhi(u);
    }
    float sm = 0.f;
    #pragma unroll
    for (int i = 0; i < 24; ++i) sm += v[i];
    sm += __shfl_xor(sm, 1, 64);
    sm += __shfl_xor(sm, 2, 64);
    float mu = sm * (1.f / CC);
    float sq = 0.f;
    #pragma unroll
    for (int i = 0; i < 24; ++i) { float d = v[i] - mu; sq += d * d; }
    sq += __shfl_xor(sq, 1, 64);
    sq += __shfl_xor(sq, 2, 64);
    float inv = rsqrtf(sq * (1.f / CC) + 1e-5f);
    u16 o[24];
    #pragma unroll
    for (int i = 0; i < 24; ++i) {
      int c = sub * 24 + i;
      o[i] = f2bf((v[i] - mu) * inv * g2[c] + b2[c]);
    }
    u16* dst = &sXn[tok * SXP + sub * 24];
    *(uint4*)(dst)      = *(const uint4*)(o);
    *(uint4*)(dst + 8)  = *(const uint4*)(o + 8);
    *(uint4*)(dst + 16) = *(const uint4*)(o + 16);
  }
  __syncthreads();   // sX1 reads complete; sH free for P3

  // ---- P3: FC1 [32x96]@[96x384] + GELU -> sH; B once per nt, 2 MFMA-triples (mt0,mt1)
  {
    bf16x8 a[2][3];
    #pragma unroll
    for (int mt = 0; mt < 2; ++mt) {
      const u16* aXn = &sXn[(mt * 16 + cl) * SXP + 8 * g];
      a[mt][0] = *(const bf16x8*)(aXn);
      a[mt][1] = *(const bf16x8*)(aXn + 32);
      a[mt][2] = *(const bf16x8*)(aXn + 64);
    }
    const int nt0 = hnt * 12;
    const u16* bPtr = fc1_wT + ((size_t)(nt0 * 16 + cl)) * CC + 8 * g;
    bf16x8 b0 = *(const bf16x8*)(bPtr);
    bf16x8 b1 = *(const bf16x8*)(bPtr + 32);
    bf16x8 b2 = *(const bf16x8*)(bPtr + 64);
    #pragma unroll
    for (int j = 0; j < 12; ++j) {
      bf16x8 c0 = b0, c1 = b1, c2 = b2;
      if (j < 11) {                       // prefetch next nt
        bPtr += 16 * CC;
        b0 = *(const bf16x8*)(bPtr);
        b1 = *(const bf16x8*)(bPtr + 32);
        b2 = *(const bf16x8*)(bPtr + 64);
      }
      const int nt = nt0 + j;
      const float bj = fc1_b[nt * 16 + cl];
      #pragma unroll
      for (int mt = 0; mt < 2; ++mt) {
        f32x4 acc = {0.f, 0.f, 0.f, 0.f};
        acc = MFMA16(a[mt][0], c0, acc);
        acc = MFMA16(a[mt][1], c1, acc);
        acc = MFMA16(a[mt][2], c2, acc);
        #pragma unroll
        for (int r = 0; r < 4; ++r) {
          float v = acc[r] + bj;
          // tanh-GELU: v*e/(e+1), e = exp(v*(1.59576912 + 0.07135481*v^2))
          float p2 = v * v;
          float aa = v * fmaf(0.07135481f, p2, 1.59576912f);
          float e  = __expf(aa);
          float gl = v * e * __builtin_amdgcn_rcpf(e + 1.f);
          sH[(mt * 16 + 4 * g + r) * SHP + nt * 16 + cl] = f2bf(gl);
        }
      }
    }
  }
  __syncthreads();

  // ---- P4: FC2 [32x384]@[384x96] in 4 k-quarters; B once per (nt,q), 2 MFMAs each
  {
    f32x4 acc2[3][2];
    #pragma unroll
    for (int j = 0; j < 3; ++j)
      #pragma unroll
      for (int mt = 0; mt < 2; ++mt) { f32x4 z = {0.f, 0.f, 0.f, 0.f}; acc2[j][mt] = z; }

    #pragma unroll
    for (int q = 0; q < 4; ++q) {
      bf16x8 a[2][3];
      #pragma unroll
      for (int mt = 0; mt < 2; ++mt) {
        const u16* aBase = &sH[(mt * 16 + cl) * SHP + q * 96 + 8 * g];
        a[mt][0] = *(const bf16x8*)(aBase);
        a[mt][1] = *(const bf16x8*)(aBase + 32);
        a[mt][2] = *(const bf16x8*)(aBase + 64);
      }
      #pragma unroll
      for (int j = 0; j < 3; ++j) {
        const int nt = hnt * 3 + j;
        const u16* bBase = fc2_wT + (size_t)(nt * 16 + cl) * MLPH + q * 96 + 8 * g;
        bf16x8 b0 = *(const bf16x8*)(bBase);
        bf16x8 b1 = *(const bf16x8*)(bBase + 32);
        bf16x8 b2 = *(const bf16x8*)(bBase + 64);
        #pragma unroll
        for (int mt = 0; mt < 2; ++mt) {
          acc2[j][mt] = MFMA16(a[mt][0], b0, acc2[j][mt]);
          acc2[j][mt] = MFMA16(a[mt][1], b1, acc2[j][mt]);
          acc2[j][mt] = MFMA16(a[mt][2], b2, acc2[j][mt]);
        }
      }
    }
    #pragma unroll
    for (int j = 0; j < 3; ++j) {
      const int nt = hnt * 3 + j;
      const float bc = fc2_b[nt * 16 + cl];
      #pragma unroll
      for (int mt = 0; mt < 2; ++mt)
        #pragma unroll
        for (int r = 0; r < 4; ++r)
          out[(size_t)nr[mt][r] * CC + nt * 16 + cl] = x1v[j][mt][r] + acc2[j][mt][r] + bc;
    }
  }
}

extern "C" void kernel_launch(void* const* d_in, const int* in_sizes, int n_in,
                              void* d_out, int out_size, void* d_ws, size_t ws_size,
                              hipStream_t stream) {
  const float* x      = (const float*)d_in[0];
  const float* g1     = (const float*)d_in[1];
  const float* b1     = (const float*)d_in[2];
  const float* qkv_w  = (const float*)d_in[3];
  const float* qkv_b  = (const float*)d_in[4];
  const float* rpb    = (const float*)d_in[5];
  const float* proj_w = (const float*)d_in[6];
  const float* proj_b = (const float*)d_in[7];
  const float* g2     = (const float*)d_in[8];
  const float* b2     = (const float*)d_in[9];
  const float* fc1_w  = (const float*)d_in[10];
  const float* fc1_b  = (const float*)d_in[11];
  const float* fc2_w  = (const float*)d_in[12];
  const float* fc2_b  = (const float*)d_in[13];

  char* ws = (char*)d_ws;
  u16*   att    = (u16*)ws;                                   // NTOK*96 bf16 = 38.5 MB
  u16*   xnw    = (u16*)(ws + (size_t)NTOK * CC * 2);         // NWIN*112*96 bf16 = 44 MB
  char*  wtail  = ws + (size_t)NTOK * CC * 2 + (size_t)NWIN * 112 * CC * 2;
  float* biasTP = (float*)wtail;                              // 3*112*128*4 = 172032 B
  u16*   qkv_wT = (u16*)(wtail + 172032);                     // 55296 B
  u16*   proj_wT= (u16*)(wtail + 172032 + 55296);             // 18432 B
  u16*   fc1_wT = (u16*)(wtail + 172032 + 55296 + 18432);     // 73728 B
  u16*   fc2_wT = (u16*)(wtail + 172032 + 55296 + 18432 + 73728); // 73728 B

  wprep_kernel<<<(27648 + 9216 + 36864 + 36864 + 255) / 256, 256, 0, stream>>>(
      qkv_w, proj_w, fc1_w, fc2_w, qkv_wT, proj_wT, fc1_wT, fc2_wT);
  bias_kernel<<<(NHEADS * 112 * 128 + 255) / 256, 256, 0, stream>>>(rpb, biasTP);
  ln1_kernel<<<NWIN * 112 / 64, 256, 0, stream>>>(x, g1, b1, xnw);
  attn_kernel<<<NWIN * NHEADS, 256, 0, stream>>>(xnw, qkv_wT, qkv_b, biasTP, att);
  pm_kernel<<<NTOK / 32, 128, 0, stream>>>(att, proj_wT, proj_b, x, g2, b2,
                                           fc1_wT, fc1_b, fc2_wT, fc2_b, (float*)d_out);
}